// Round 6
// baseline (2623.502 us; speedup 1.0000x reference)
//
#include <hip/hip_runtime.h>

// LSTMPredictor: B=1024, T=512, IN=19, H=128, OUT=7 (fp32 in/out)
// FUSED, 256 blocks x 1024 threads (16 waves), R=4 rows/block, 1 block/CU.
// Waves 0-7: layer1 (16 cols each, weights in VGPR; bias+Wx folded into MFMA
//            C-input -> recurrent chain = 4 dependent MFMAs). Wave 0: y-duty.
// Waves 8-15: layer2 (wi2+wh2 in VGPR; two parallel depth-4 K-chains summed).
// h1/h2 in 2x2KB LDS double buffers; x staged to LDS fp16 once. 513 barriers.
// D-layout row-duplication invariant (R3-proven): A-frag rows dup mod 4 ->
// acc_g[r] at every lane holds D_g[r][col]; lane (lg,lc) selects reg lg (sel4).

typedef _Float16 half8 __attribute__((ext_vector_type(8)));
typedef float f32x4 __attribute__((ext_vector_type(4)));

#define MFMA16(a, b, c) __builtin_amdgcn_mfma_f32_16x16x32_f16((a), (b), (c), 0, 0, 0)
#define BARRIER() asm volatile("s_waitcnt lgkmcnt(0)\ns_barrier" ::: "memory")

__device__ __forceinline__ float sigf(float x) {
  return __builtin_amdgcn_rcpf(1.f + __expf(-x));   // NaN-free at +/-inf
}
__device__ __forceinline__ float tanhf_(float x) {
  return 1.f - 2.f * __builtin_amdgcn_rcpf(1.f + __expf(2.f * x));  // NaN-free
}
// acc_g[r] == D_g[r][lc] at every lane (duplication invariant) -> pick reg lg.
__device__ __forceinline__ float sel4(const f32x4 a, const int lg) {
  const float v01 = (lg & 1) ? a[1] : a[0];
  const float v23 = (lg & 1) ? a[3] : a[2];
  return (lg & 2) ? v23 : v01;
}

__global__ __launch_bounds__(1024) void lstm_fused16(
    const float* __restrict__ x,        // [1024,512,19]
    const float* __restrict__ Wih1,     // [512,19]
    const float* __restrict__ Whh1,     // [512,128]
    const float* __restrict__ bih1, const float* __restrict__ bhh1,
    const float* __restrict__ Wih2,     // [512,128]
    const float* __restrict__ Whh2,     // [512,128]
    const float* __restrict__ bih2, const float* __restrict__ bhh2,
    const float* __restrict__ Wlin,     // [7,128]
    const float* __restrict__ blin,     // [7]
    float* __restrict__ out)            // [1024, 3584]
{
  __shared__ _Float16 xls[512 * 96];    // 98,304 B: x A-frags [t][cg=cc*4+rr][j]
  __shared__ _Float16 h1b[2048];        // 4 KB double buffer (frag layout)
  __shared__ _Float16 h2b[2048];
  const int tid = threadIdx.x, bid = blockIdx.x;
  const int wv = tid >> 6, lane = tid & 63;
  const int lg = lane >> 4, lc = lane & 15;
  const int off0 = lg * 32 + (lc & 3) * 8;           // A-frag read offset (halfs)
  const int wcol = (wv & 7) * 16 + lc;               // this wave's hidden column
  const int woff = ((wcol >> 3) * 4 + lg) * 8 + (wcol & 7);  // h write offset

  // Stage x rows [4bid..4bid+3] as fp16 A-frags (k padded to 24, zeros k>=19).
  for (int i2 = tid; i2 < 512 * 96; i2 += 1024) {
    const int t = i2 / 96, r = i2 - t * 96;
    const int cc = r >> 5, rr = (r >> 3) & 3, j = r & 7;
    const int k = cc * 8 + j;
    float v = 0.f;
    if (k < 19) v = x[((size_t)(bid * 4 + rr) * 512 + t) * 19 + k];
    xls[i2] = (_Float16)v;
  }
  for (int i = tid; i < 2048; i += 1024) {
    h1b[i] = (_Float16)0.f;
    h2b[i] = (_Float16)0.f;
  }

  const f32x4 fz = {0.f, 0.f, 0.f, 0.f};

  if (wv < 8) {
    // ================= Layer-1 role (+ y duty on wave 0) =================
    half8 wih_f[4], whh_f[4][4];
    f32x4 bias_v[4];
#pragma unroll
    for (int g = 0; g < 4; ++g) {
      const int n = g * 128 + wcol;
      const float bb = bih1[n] + bhh1[n];
      bias_v[g] = (f32x4){bb, bb, bb, bb};
      half8 f;
#pragma unroll
      for (int j = 0; j < 8; ++j) {
        const int k = lg * 8 + j;
        f[j] = (_Float16)((k < 19) ? Wih1[n * 19 + k] : 0.f);
      }
      wih_f[g] = f;
#pragma unroll
      for (int kk = 0; kk < 4; ++kk) {
        const float* p = Whh1 + n * 128 + kk * 32 + lg * 8;
        half8 f2;
#pragma unroll
        for (int j = 0; j < 8; ++j) f2[j] = (_Float16)p[j];
        whh_f[g][kk] = f2;
      }
    }
    const bool yv = (lc < 7);
    float ybias = 0.f;
    half8 wl_f[4] = {};
    if (wv == 0) {
      ybias = yv ? blin[lc] : 0.f;
#pragma unroll
      for (int kk = 0; kk < 4; ++kk) {
        half8 f;
#pragma unroll
        for (int j = 0; j < 8; ++j)
          f[j] = yv ? (_Float16)Wlin[lc * 128 + kk * 32 + lg * 8 + j] : (_Float16)0.f;
        wl_f[kk] = f;
      }
    }
    __syncthreads();

    float c1 = 0.f;
    const bool xv = (lg < 3);
    const _Float16* xbase = xls + off0;
    float* outp = out + (size_t)(bid * 4) * 3584 + lc;

#pragma unroll 1
    for (int it = 0; it < 513; ++it) {
      if (it < 512) {
        half8 ax = {};
        if (xv) ax = *(const half8*)(xbase + it * 96);
        const _Float16* rd = h1b + (((it & 1) ^ 1) << 10) + off0;  // h1(it-1)
        const half8 hb0 = *(const half8*)(rd);
        const half8 hb1 = *(const half8*)(rd + 128);
        const half8 hb2 = *(const half8*)(rd + 256);
        const half8 hb3 = *(const half8*)(rd + 384);
        // off-chain: bias + Wx*x(t) as C-input; chain = 4 dependent MFMAs
        f32x4 a0 = MFMA16(ax, wih_f[0], bias_v[0]);
        f32x4 a1 = MFMA16(ax, wih_f[1], bias_v[1]);
        f32x4 a2 = MFMA16(ax, wih_f[2], bias_v[2]);
        f32x4 a3 = MFMA16(ax, wih_f[3], bias_v[3]);
        a0 = MFMA16(hb0, whh_f[0][0], a0); a1 = MFMA16(hb0, whh_f[1][0], a1);
        a2 = MFMA16(hb0, whh_f[2][0], a2); a3 = MFMA16(hb0, whh_f[3][0], a3);
        a0 = MFMA16(hb1, whh_f[0][1], a0); a1 = MFMA16(hb1, whh_f[1][1], a1);
        a2 = MFMA16(hb1, whh_f[2][1], a2); a3 = MFMA16(hb1, whh_f[3][1], a3);
        a0 = MFMA16(hb2, whh_f[0][2], a0); a1 = MFMA16(hb2, whh_f[1][2], a1);
        a2 = MFMA16(hb2, whh_f[2][2], a2); a3 = MFMA16(hb2, whh_f[3][2], a3);
        a0 = MFMA16(hb3, whh_f[0][3], a0); a1 = MFMA16(hb3, whh_f[1][3], a1);
        a2 = MFMA16(hb3, whh_f[2][3], a2); a3 = MFMA16(hb3, whh_f[3][3], a3);
        const float gi = sel4(a0, lg);
        const float gf = sel4(a1, lg);
        const float gg = sel4(a2, lg);
        const float go = sel4(a3, lg);
        const float I = sigf(gi), F = sigf(gf), G = tanhf_(gg), O = sigf(go);
        c1 = F * c1 + I * G;
        const float h = O * tanhf_(c1);
        h1b[((it & 1) << 10) + woff] = (_Float16)h;
      }
      // y(it-2) from h2(it-2) in h2b[it&1] (stable this iteration)
      if (wv == 0 && it >= 2) {
        const _Float16* r2 = h2b + ((it & 1) << 10) + off0;
        const half8 y0 = *(const half8*)(r2);
        const half8 y1 = *(const half8*)(r2 + 128);
        const half8 y2 = *(const half8*)(r2 + 256);
        const half8 y3 = *(const half8*)(r2 + 384);
        f32x4 ya = {ybias, ybias, ybias, ybias};
        ya = MFMA16(y0, wl_f[0], ya);
        ya = MFMA16(y1, wl_f[1], ya);
        ya = MFMA16(y2, wl_f[2], ya);
        ya = MFMA16(y3, wl_f[3], ya);
        if (lg == 0 && yv) {
#pragma unroll
          for (int j = 0; j < 4; ++j)
            outp[(size_t)j * 3584 + (size_t)(it - 2) * 7] = ya[j];
        }
      }
      BARRIER();
    }
    // final y(511): h2(511) written at it=512 into h2b[1024..]
    if (wv == 0) {
      const _Float16* r2 = h2b + 1024 + off0;
      const half8 y0 = *(const half8*)(r2);
      const half8 y1 = *(const half8*)(r2 + 128);
      const half8 y2 = *(const half8*)(r2 + 256);
      const half8 y3 = *(const half8*)(r2 + 384);
      f32x4 ya = {ybias, ybias, ybias, ybias};
      ya = MFMA16(y0, wl_f[0], ya);
      ya = MFMA16(y1, wl_f[1], ya);
      ya = MFMA16(y2, wl_f[2], ya);
      ya = MFMA16(y3, wl_f[3], ya);
      if (lg == 0 && yv) {
#pragma unroll
        for (int j = 0; j < 4; ++j)
          outp[(size_t)j * 3584 + (size_t)511 * 7] = ya[j];
      }
    }
  } else {
    // ================= Layer-2 role (one step behind) =================
    half8 wi_f[4][4], wh_f[4][4];
    f32x4 bias_v[4];
#pragma unroll
    for (int g = 0; g < 4; ++g) {
      const int n = g * 128 + wcol;
      const float bb = bih2[n] + bhh2[n];
      bias_v[g] = (f32x4){bb, bb, bb, bb};
#pragma unroll
      for (int kk = 0; kk < 4; ++kk) {
        const float* pi = Wih2 + n * 128 + kk * 32 + lg * 8;
        const float* ph = Whh2 + n * 128 + kk * 32 + lg * 8;
        half8 fi, fh;
#pragma unroll
        for (int j = 0; j < 8; ++j) { fi[j] = (_Float16)pi[j]; fh[j] = (_Float16)ph[j]; }
        wi_f[g][kk] = fi;
        wh_f[g][kk] = fh;
      }
    }
    __syncthreads();

    float c2 = 0.f;
#pragma unroll 1
    for (int it = 0; it < 513; ++it) {
      if (it >= 1) {
        // t2 = it-1: h1(t2) in h1b[(it-1)&1]; h2(t2-1) in h2b[it&1]
        const _Float16* rd1 = h1b + (((it & 1) ^ 1) << 10) + off0;
        const _Float16* rd2 = h2b + ((it & 1) << 10) + off0;
        const half8 p0 = *(const half8*)(rd1);
        const half8 p1 = *(const half8*)(rd1 + 128);
        const half8 p2 = *(const half8*)(rd1 + 256);
        const half8 p3 = *(const half8*)(rd1 + 384);
        const half8 q0 = *(const half8*)(rd2);
        const half8 q1 = *(const half8*)(rd2 + 128);
        const half8 q2 = *(const half8*)(rd2 + 256);
        const half8 q3 = *(const half8*)(rd2 + 384);
        // two parallel depth-4 chains per gate: wi2*h1 (with bias) || wh2*h2
        f32x4 a0 = MFMA16(p0, wi_f[0][0], bias_v[0]);
        f32x4 a1 = MFMA16(p0, wi_f[1][0], bias_v[1]);
        f32x4 a2 = MFMA16(p0, wi_f[2][0], bias_v[2]);
        f32x4 a3 = MFMA16(p0, wi_f[3][0], bias_v[3]);
        f32x4 b0 = MFMA16(q0, wh_f[0][0], fz);
        f32x4 b1 = MFMA16(q0, wh_f[1][0], fz);
        f32x4 b2 = MFMA16(q0, wh_f[2][0], fz);
        f32x4 b3 = MFMA16(q0, wh_f[3][0], fz);
        a0 = MFMA16(p1, wi_f[0][1], a0); a1 = MFMA16(p1, wi_f[1][1], a1);
        a2 = MFMA16(p1, wi_f[2][1], a2); a3 = MFMA16(p1, wi_f[3][1], a3);
        b0 = MFMA16(q1, wh_f[0][1], b0); b1 = MFMA16(q1, wh_f[1][1], b1);
        b2 = MFMA16(q1, wh_f[2][1], b2); b3 = MFMA16(q1, wh_f[3][1], b3);
        a0 = MFMA16(p2, wi_f[0][2], a0); a1 = MFMA16(p2, wi_f[1][2], a1);
        a2 = MFMA16(p2, wi_f[2][2], a2); a3 = MFMA16(p2, wi_f[3][2], a3);
        b0 = MFMA16(q2, wh_f[0][2], b0); b1 = MFMA16(q2, wh_f[1][2], b1);
        b2 = MFMA16(q2, wh_f[2][2], b2); b3 = MFMA16(q2, wh_f[3][2], b3);
        a0 = MFMA16(p3, wi_f[0][3], a0); a1 = MFMA16(p3, wi_f[1][3], a1);
        a2 = MFMA16(p3, wi_f[2][3], a2); a3 = MFMA16(p3, wi_f[3][3], a3);
        b0 = MFMA16(q3, wh_f[0][3], b0); b1 = MFMA16(q3, wh_f[1][3], b1);
        b2 = MFMA16(q3, wh_f[2][3], b2); b3 = MFMA16(q3, wh_f[3][3], b3);
        const f32x4 s0 = a0 + b0, s1 = a1 + b1, s2 = a2 + b2, s3 = a3 + b3;
        const float gi = sel4(s0, lg);
        const float gf = sel4(s1, lg);
        const float gg = sel4(s2, lg);
        const float go = sel4(s3, lg);
        const float I = sigf(gi), F = sigf(gf), G = tanhf_(gg), O = sigf(go);
        c2 = F * c2 + I * G;
        const float h = O * tanhf_(c2);
        h2b[(((it & 1) ^ 1) << 10) + woff] = (_Float16)h;
      }
      BARRIER();
    }
  }
}

extern "C" void kernel_launch(void* const* d_in, const int* in_sizes, int n_in,
                              void* d_out, int out_size, void* d_ws, size_t ws_size,
                              hipStream_t stream) {
  (void)in_sizes; (void)n_in; (void)out_size; (void)d_ws; (void)ws_size;
  const float* x     = (const float*)d_in[0];
  const float* W_ih1 = (const float*)d_in[1];
  const float* W_hh1 = (const float*)d_in[2];
  const float* b_ih1 = (const float*)d_in[3];
  const float* b_hh1 = (const float*)d_in[4];
  const float* W_ih2 = (const float*)d_in[5];
  const float* W_hh2 = (const float*)d_in[6];
  const float* b_ih2 = (const float*)d_in[7];
  const float* b_hh2 = (const float*)d_in[8];
  const float* W_lin = (const float*)d_in[9];
  const float* b_lin = (const float*)d_in[10];
  float* out = (float*)d_out;

  lstm_fused16<<<256, 1024, 0, stream>>>(x, W_ih1, W_hh1, b_ih1, b_hh1,
                                         W_ih2, W_hh2, b_ih2, b_hh2,
                                         W_lin, b_lin, out);
}

// Round 7
// 1200.288 us; speedup vs baseline: 2.1857x; 2.1857x over previous
//
#include <hip/hip_runtime.h>

// LSTMPredictor: B=1024, T=512, IN=19, H=128, OUT=7 (fp32 in/out)
// Two kernels (R3 structure) with EXPLICIT register-residency contracts:
//  L1: R=2 rows/block, 512 blocks x 512 thr, waves_per_eu(4,4) -> 2 blk/CU,
//      ~110 VGPR/wave (fits 128 cap), independent blocks interleave stalls.
//  L2: R=4 rows/block, 256 blocks x 512 thr, waves_per_eu(2,2) -> 256 VGPR
//      budget so wi2+wh2 (128 weight VGPRs) stay resident; weight frags
//      pinned with opaque-def asm so the allocator can't sink the loads.
// D-layout row-duplication invariant (R3-proven): A-frag rows dup mod R ->
// acc_g[r] at every lane holds D_g[r][col]; lane selects its own register.

typedef _Float16 half8 __attribute__((ext_vector_type(8)));
typedef float f32x4 __attribute__((ext_vector_type(4)));

#define MFMA16(a, b, c) __builtin_amdgcn_mfma_f32_16x16x32_f16((a), (b), (c), 0, 0, 0)
#define BARRIER() asm volatile("s_waitcnt lgkmcnt(0)\ns_barrier" ::: "memory")

__device__ __forceinline__ void pin(half8& v) { asm volatile("" : "+v"(v)); }
__device__ __forceinline__ void pinf(f32x4& v) { asm volatile("" : "+v"(v)); }

__device__ __forceinline__ float sigf(float x) {
  return __builtin_amdgcn_rcpf(1.f + __expf(-x));   // NaN-free at +/-inf
}
__device__ __forceinline__ float tanhf_(float x) {
  return 1.f - 2.f * __builtin_amdgcn_rcpf(1.f + __expf(2.f * x));  // NaN-free
}
// R=4 variant: acc_g[r] == D_g[r][lc] at every lane -> pick reg lg.
__device__ __forceinline__ float sel4(const f32x4 a, const int lg) {
  const float v01 = (lg & 1) ? a[1] : a[0];
  const float v23 = (lg & 1) ? a[3] : a[2];
  return (lg & 2) ? v23 : v01;
}

// ---------------- Layer 1: R=2, 512 blocks, 4 waves/EU ----------------
__global__ __attribute__((amdgpu_waves_per_eu(4, 4))) __launch_bounds__(512)
void lstm_layer1_kernel(
    const float* __restrict__ x,        // [1024,512,19]
    const float* __restrict__ Wih,      // [512,19]
    const float* __restrict__ Whh,      // [512,128]
    const float* __restrict__ bih, const float* __restrict__ bhh,
    _Float16* __restrict__ h1g)         // [512][1024][128] fp16 (T-major)
{
  __shared__ _Float16 xls[512 * 48];    // 49,152 B: x A-frags [t][cc][r][j]
  __shared__ _Float16 hbuf[2][256];     // 1 KiB: [buf][(u>>3)*2 + r][j]
  const int tid = threadIdx.x, bid = blockIdx.x;
  const int wv = tid >> 6, lane = tid & 63;
  const int lg = lane >> 4, lc = lane & 15;
  const int col = wv * 16 + lc;                   // hidden unit owned
  const int r2 = lc & 1;                          // A-frag row (dup mod 2)
  const int off0 = (lg * 2 + r2) * 8;             // frag read offset (halfs)
  const int woff = ((col >> 3) * 2 + (lg & 1)) * 8 + (col & 7);

  // Weight B-frags: col n = g*128+col, k = lg*8+j; bias folded as MFMA C-in.
  half8 wih_f[4], whh_f[4][4];
  f32x4 bias_v[4];
#pragma unroll
  for (int g = 0; g < 4; ++g) {
    const int n = g * 128 + col;
    const float bb = bih[n] + bhh[n];
    bias_v[g] = (f32x4){bb, bb, bb, bb};
    half8 f;
#pragma unroll
    for (int j = 0; j < 8; ++j) {
      const int k = lg * 8 + j;
      f[j] = (_Float16)((k < 19) ? Wih[n * 19 + k] : 0.f);
    }
    wih_f[g] = f;
#pragma unroll
    for (int kk = 0; kk < 4; ++kk) {
      const float* p = Whh + n * 128 + kk * 32 + lg * 8;
      half8 f2;
#pragma unroll
      for (int j = 0; j < 8; ++j) f2[j] = (_Float16)p[j];
      whh_f[g][kk] = f2;
    }
    pin(wih_f[g]);
    pin(whh_f[g][0]); pin(whh_f[g][1]); pin(whh_f[g][2]); pin(whh_f[g][3]);
    pinf(bias_v[g]);
  }

  // Stage x rows {2bid, 2bid+1} as fp16 A-frags: idx = t*48 + (cc*2+r)*8 + j.
  for (int i2 = tid; i2 < 512 * 48; i2 += 512) {
    const int t = i2 / 48, rem = i2 - t * 48;
    const int cc = rem >> 4, r = (rem >> 3) & 1, j = rem & 7;
    const int k = cc * 8 + j;
    float v = 0.f;
    if (k < 19) v = x[((size_t)(bid * 2 + r) * 512 + t) * 19 + k];
    xls[i2] = (_Float16)v;
  }
  for (int i = tid; i < 512; i += 512) {
    hbuf[0][i] = (_Float16)0.f;
    hbuf[1][i] = (_Float16)0.f;
  }
  __syncthreads();

  float c = 0.f;
  const bool xv = (lg < 3);
  const bool wr2 = (lg < 2);
  _Float16* h1p = h1g + (size_t)(bid * 2 + (lg & 1)) * 128 + col;
  const _Float16* xbase = xls + off0;

#pragma unroll 1
  for (int t = 0; t < 512; ++t) {
    const _Float16* rd = &hbuf[(t & 1) ^ 1][0] + off0;
    const half8 hb0 = *(const half8*)(rd);
    const half8 hb1 = *(const half8*)(rd + 64);
    const half8 hb2 = *(const half8*)(rd + 128);
    const half8 hb3 = *(const half8*)(rd + 192);
    half8 ax = {};
    if (xv) ax = *(const half8*)(xbase + t * 48);
    f32x4 a0 = MFMA16(ax, wih_f[0], bias_v[0]);
    f32x4 a1 = MFMA16(ax, wih_f[1], bias_v[1]);
    f32x4 a2 = MFMA16(ax, wih_f[2], bias_v[2]);
    f32x4 a3 = MFMA16(ax, wih_f[3], bias_v[3]);
    a0 = MFMA16(hb0, whh_f[0][0], a0); a1 = MFMA16(hb0, whh_f[1][0], a1);
    a2 = MFMA16(hb0, whh_f[2][0], a2); a3 = MFMA16(hb0, whh_f[3][0], a3);
    a0 = MFMA16(hb1, whh_f[0][1], a0); a1 = MFMA16(hb1, whh_f[1][1], a1);
    a2 = MFMA16(hb1, whh_f[2][1], a2); a3 = MFMA16(hb1, whh_f[3][1], a3);
    a0 = MFMA16(hb2, whh_f[0][2], a0); a1 = MFMA16(hb2, whh_f[1][2], a1);
    a2 = MFMA16(hb2, whh_f[2][2], a2); a3 = MFMA16(hb2, whh_f[3][2], a3);
    a0 = MFMA16(hb3, whh_f[0][3], a0); a1 = MFMA16(hb3, whh_f[1][3], a1);
    a2 = MFMA16(hb3, whh_f[2][3], a2); a3 = MFMA16(hb3, whh_f[3][3], a3);
    // D rows dup mod 2 -> reg r holds gates[r&1]; row (lg&1) is at reg lg&1.
    const float gi = (lg & 1) ? a0[1] : a0[0];
    const float gf = (lg & 1) ? a1[1] : a1[0];
    const float gg = (lg & 1) ? a2[1] : a2[0];
    const float go = (lg & 1) ? a3[1] : a3[0];
    const float I = sigf(gi), F = sigf(gf), G = tanhf_(gg), O = sigf(go);
    c = F * c + I * G;
    const float h = O * tanhf_(c);
    if (wr2) {
      const _Float16 h16 = (_Float16)h;
      hbuf[t & 1][woff] = h16;
      h1p[(size_t)t * 131072] = h16;
    }
    BARRIER();
  }
}

// ---------------- Layer 2 + Linear: R=4, 256 blocks, 2 waves/EU ----------------
__global__ __attribute__((amdgpu_waves_per_eu(2, 2))) __launch_bounds__(512)
void lstm_layer2_kernel(
    const _Float16* __restrict__ h1g,   // [512][1024][128]
    const float* __restrict__ Wih,      // [512,128]
    const float* __restrict__ Whh,      // [512,128]
    const float* __restrict__ bih, const float* __restrict__ bhh,
    const float* __restrict__ Wlin,     // [7,128]
    const float* __restrict__ blin,     // [7]
    float* __restrict__ out)            // [1024, 3584]
{
  __shared__ _Float16 hbuf[2][512];     // 2 KiB: [buf][(u>>3)*4 + r][j]
  const int tid = threadIdx.x, bid = blockIdx.x;
  const int wv = tid >> 6, lane = tid & 63;
  const int lg = lane >> 4, lc = lane & 15;
  const int col = wv * 16 + lc;
  const int off0 = lg * 32 + (lc & 3) * 8;
  const int woff = ((col >> 3) * 4 + lg) * 8 + (col & 7);

  half8 wi_f[4][4], wh_f[4][4];
  f32x4 bias_v[4];
#pragma unroll
  for (int g = 0; g < 4; ++g) {
    const int n = g * 128 + col;
    const float bb = bih[n] + bhh[n];
    bias_v[g] = (f32x4){bb, bb, bb, bb};
#pragma unroll
    for (int kk = 0; kk < 4; ++kk) {
      const float* pi = Wih + n * 128 + kk * 32 + lg * 8;
      const float* ph = Whh + n * 128 + kk * 32 + lg * 8;
      half8 fi, fh;
#pragma unroll
      for (int j = 0; j < 8; ++j) { fi[j] = (_Float16)pi[j]; fh[j] = (_Float16)ph[j]; }
      wi_f[g][kk] = fi;
      wh_f[g][kk] = fh;
    }
    pin(wi_f[g][0]); pin(wi_f[g][1]); pin(wi_f[g][2]); pin(wi_f[g][3]);
    pin(wh_f[g][0]); pin(wh_f[g][1]); pin(wh_f[g][2]); pin(wh_f[g][3]);
    pinf(bias_v[g]);
  }
  half8 wl_f[4];
  const bool yv = (lc < 7);
  const float ybias = yv ? blin[lc] : 0.f;
#pragma unroll
  for (int kk = 0; kk < 4; ++kk) {
    half8 f;
#pragma unroll
    for (int j = 0; j < 8; ++j)
      f[j] = yv ? (_Float16)Wlin[lc * 128 + kk * 32 + lg * 8 + j] : (_Float16)0.f;
    wl_f[kk] = f;
    pin(wl_f[kk]);
  }

  for (int i = tid; i < 512; i += 512) {
    hbuf[0][i] = (_Float16)0.f;
    hbuf[1][i] = (_Float16)0.f;
  }
  __syncthreads();

  float c = 0.f;
  const _Float16* h1p = h1g + (size_t)(bid * 4 + (lc & 3)) * 128 + lg * 8;
  const f32x4 fz = {0.f, 0.f, 0.f, 0.f};

  half8 iA0 = *(const half8*)(h1p);
  half8 iA1 = *(const half8*)(h1p + 32);
  half8 iA2 = *(const half8*)(h1p + 64);
  half8 iA3 = *(const half8*)(h1p + 96);
  half8 iB0 = {}, iB1 = {}, iB2 = {}, iB3 = {};

#define L2_STEP(T, RD, WR, IC0, IC1, IC2, IC3, IN0, IN1, IN2, IN3)            \
  {                                                                           \
    const _Float16* rd = (RD) + off0;                                         \
    const half8 hb0 = *(const half8*)(rd);                                    \
    const half8 hb1 = *(const half8*)(rd + 128);                              \
    const half8 hb2 = *(const half8*)(rd + 256);                              \
    const half8 hb3 = *(const half8*)(rd + 384);                              \
    const size_t tn = (size_t)((T) + 1 < 512 ? (T) + 1 : 511) * 131072;       \
    IN0 = *(const half8*)(h1p + tn);                                          \
    IN1 = *(const half8*)(h1p + tn + 32);                                     \
    IN2 = *(const half8*)(h1p + tn + 64);                                     \
    IN3 = *(const half8*)(h1p + tn + 96);                                     \
    /* two parallel depth-4 chains: wi*h1 (regs, bias C-in) || wh*h2 (LDS) */ \
    f32x4 a0 = MFMA16(IC0, wi_f[0][0], bias_v[0]);                            \
    f32x4 a1 = MFMA16(IC0, wi_f[1][0], bias_v[1]);                            \
    f32x4 a2 = MFMA16(IC0, wi_f[2][0], bias_v[2]);                            \
    f32x4 a3 = MFMA16(IC0, wi_f[3][0], bias_v[3]);                            \
    f32x4 b0 = MFMA16(hb0, wh_f[0][0], fz);                                   \
    f32x4 b1 = MFMA16(hb0, wh_f[1][0], fz);                                   \
    f32x4 b2 = MFMA16(hb0, wh_f[2][0], fz);                                   \
    f32x4 b3 = MFMA16(hb0, wh_f[3][0], fz);                                   \
    a0 = MFMA16(IC1, wi_f[0][1], a0); a1 = MFMA16(IC1, wi_f[1][1], a1);       \
    a2 = MFMA16(IC1, wi_f[2][1], a2); a3 = MFMA16(IC1, wi_f[3][1], a3);       \
    b0 = MFMA16(hb1, wh_f[0][1], b0); b1 = MFMA16(hb1, wh_f[1][1], b1);       \
    b2 = MFMA16(hb1, wh_f[2][1], b2); b3 = MFMA16(hb1, wh_f[3][1], b3);       \
    a0 = MFMA16(IC2, wi_f[0][2], a0); a1 = MFMA16(IC2, wi_f[1][2], a1);       \
    a2 = MFMA16(IC2, wi_f[2][2], a2); a3 = MFMA16(IC2, wi_f[3][2], a3);       \
    b0 = MFMA16(hb2, wh_f[0][2], b0); b1 = MFMA16(hb2, wh_f[1][2], b1);       \
    b2 = MFMA16(hb2, wh_f[2][2], b2); b3 = MFMA16(hb2, wh_f[3][2], b3);       \
    a0 = MFMA16(IC3, wi_f[0][3], a0); a1 = MFMA16(IC3, wi_f[1][3], a1);       \
    a2 = MFMA16(IC3, wi_f[2][3], a2); a3 = MFMA16(IC3, wi_f[3][3], a3);       \
    b0 = MFMA16(hb3, wh_f[0][3], b0); b1 = MFMA16(hb3, wh_f[1][3], b1);       \
    b2 = MFMA16(hb3, wh_f[2][3], b2); b3 = MFMA16(hb3, wh_f[3][3], b3);       \
    if (wv == 0 && (T) > 0) {                                                 \
      f32x4 ya = {ybias, ybias, ybias, ybias};                                \
      ya = MFMA16(hb0, wl_f[0], ya);                                          \
      ya = MFMA16(hb1, wl_f[1], ya);                                          \
      ya = MFMA16(hb2, wl_f[2], ya);                                          \
      ya = MFMA16(hb3, wl_f[3], ya);                                          \
      if (lg == 0 && yv) {                                                    \
        _Pragma("unroll")                                                     \
        for (int j = 0; j < 4; ++j)                                           \
          out[(size_t)(bid * 4 + j) * 3584 + (size_t)((T)-1) * 7 + lc] = ya[j]; \
      }                                                                       \
    }                                                                         \
    const f32x4 s0 = a0 + b0, s1 = a1 + b1, s2 = a2 + b2, s3 = a3 + b3;       \
    const float gi = sel4(s0, lg);                                            \
    const float gf = sel4(s1, lg);                                            \
    const float gg = sel4(s2, lg);                                            \
    const float go = sel4(s3, lg);                                            \
    const float I = sigf(gi), F = sigf(gf), G = tanhf_(gg), O = sigf(go);     \
    c = F * c + I * G;                                                        \
    const float h = O * tanhf_(c);                                            \
    (WR)[woff] = (_Float16)h;                                                 \
    BARRIER();                                                                \
  }

  _Float16* hb0p = &hbuf[0][0];
#pragma unroll 1
  for (int t = 0; t < 512; t += 2) {
    L2_STEP(t, hb0p + 512, hb0p, iA0, iA1, iA2, iA3, iB0, iB1, iB2, iB3);
    L2_STEP(t + 1, hb0p, hb0p + 512, iB0, iB1, iB2, iB3, iA0, iA1, iA2, iA3);
  }
#undef L2_STEP

  // final y(511) from h2(511) in hbuf[1]
  if (wv == 0) {
    const _Float16* rd = hb0p + 512 + off0;
    const half8 hb0 = *(const half8*)(rd);
    const half8 hb1 = *(const half8*)(rd + 128);
    const half8 hb2 = *(const half8*)(rd + 256);
    const half8 hb3 = *(const half8*)(rd + 384);
    f32x4 ya = {ybias, ybias, ybias, ybias};
    ya = MFMA16(hb0, wl_f[0], ya);
    ya = MFMA16(hb1, wl_f[1], ya);
    ya = MFMA16(hb2, wl_f[2], ya);
    ya = MFMA16(hb3, wl_f[3], ya);
    if (lg == 0 && yv) {
#pragma unroll
      for (int j = 0; j < 4; ++j)
        out[(size_t)(bid * 4 + j) * 3584 + (size_t)511 * 7 + lc] = ya[j];
    }
  }
}

extern "C" void kernel_launch(void* const* d_in, const int* in_sizes, int n_in,
                              void* d_out, int out_size, void* d_ws, size_t ws_size,
                              hipStream_t stream) {
  (void)in_sizes; (void)n_in; (void)out_size; (void)ws_size;
  const float* x     = (const float*)d_in[0];
  const float* W_ih1 = (const float*)d_in[1];
  const float* W_hh1 = (const float*)d_in[2];
  const float* b_ih1 = (const float*)d_in[3];
  const float* b_hh1 = (const float*)d_in[4];
  const float* W_ih2 = (const float*)d_in[5];
  const float* W_hh2 = (const float*)d_in[6];
  const float* b_ih2 = (const float*)d_in[7];
  const float* b_hh2 = (const float*)d_in[8];
  const float* W_lin = (const float*)d_in[9];
  const float* b_lin = (const float*)d_in[10];
  float* out = (float*)d_out;
  _Float16* h1g = (_Float16*)d_ws;   // [512][1024][128] fp16 = 134,217,728 bytes

  lstm_layer1_kernel<<<512, 512, 0, stream>>>(x, W_ih1, W_hh1, b_ih1, b_hh1, h1g);
  lstm_layer2_kernel<<<256, 512, 0, stream>>>(h1g, W_ih2, W_hh2, b_ih2, b_hh2,
                                              W_lin, b_lin, out);
}